// Round 1
// baseline (445.886 us; speedup 1.0000x reference)
//
#include <hip/hip_runtime.h>

#define BB 4
#define NN 512
#define HH 128
#define EHH 128

typedef short short8 __attribute__((ext_vector_type(8)));
typedef float f32x4 __attribute__((ext_vector_type(4)));

__device__ __forceinline__ float fsilu(float x){
    float e = __expf(-x);
    return x * __builtin_amdgcn_rcpf(1.0f + e);
}

__device__ __forceinline__ unsigned short f2bf(float f){
    union { float f; unsigned int u; } v; v.f = f;
    unsigned int u = v.u;
    unsigned int r = (u + 0x7FFFu + ((u >> 16) & 1u)) >> 16;
    return (unsigned short)r;
}

// ---------------- prep: hi_e/hj_e projections + bf16 transposed weights ----
__global__ __launch_bounds__(128) void k_prep(
    const float* __restrict__ h,
    const float* __restrict__ We1, const float* __restrict__ be1,
    const float* __restrict__ We2, const float* __restrict__ Wc1,
    float* __restrict__ hi_e, float* __restrict__ hj_e,
    unsigned short* __restrict__ We2T, unsigned short* __restrict__ Wc1T)
{
    const int tid = threadIdx.x;
    if (blockIdx.x < BB*NN) {
        __shared__ float hrow[HH];
        const int row = blockIdx.x;
        hrow[tid] = h[row*HH + tid];
        __syncthreads();
        float a0 = be1[tid];   // fold be1 into hi_e
        float a1 = 0.f;
        #pragma unroll 8
        for (int k = 0; k < HH; ++k){
            float hv = hrow[k];
            a0 += hv * We1[k*EHH + tid];
            a1 += hv * We1[(HH + k)*EHH + tid];
        }
        hi_e[row*EHH + tid] = a0;
        hj_e[row*EHH + tid] = a1;
    } else {
        const int bid = blockIdx.x - BB*NN;   // 0..31
        for (int t = bid*128 + tid; t < 128*128; t += 32*128){
            int o = t >> 7, kk = t & 127;
            We2T[t] = f2bf(We2[kk*HH + o]);    // We2T[hcol][k]
            Wc1T[t] = f2bf(Wc1[kk*EHH + o]);   // Wc1T[out][k]
        }
    }
}

// ---------------- fused edge kernel ---------------------------------------
// grid 512 = B * (N/4).  block 256 = 4 waves in 2x2 (row-half wm, col-half wn)
__global__ __launch_bounds__(256) void k_edge(
    const float* __restrict__ x,
    const float* __restrict__ hi_e, const float* __restrict__ hj_e,
    const unsigned short* __restrict__ We2T, const unsigned short* __restrict__ Wc1T,
    const float* __restrict__ We1, const float* __restrict__ be2,
    const float* __restrict__ bc1, const float* __restrict__ Wc2,
    const float* __restrict__ bc2, const int* __restrict__ radius,
    float* __restrict__ aggb, float* __restrict__ xout)
{
    __shared__ unsigned short mA[128][136];   // m tile (bf16), stride-padded
    __shared__ float hj_s[32][132];
    __shared__ float hi_s[4][132];
    __shared__ float dx_s[128][5];            // dx0,dx1,dx2,d2
    __shared__ float xi_s[4][3], xj_s[32][3];
    __shared__ float w3_s[128], be2_s[128], bc1_s[128], wc2_s[128];
    __shared__ float gate_s[128];

    const int tid  = threadIdx.x;
    const int lane = tid & 63;
    const int wave = tid >> 6;
    const int l15  = lane & 15;
    const int g    = lane >> 4;
    const int wm   = wave >> 1, wn = wave & 1;

    const int b  = blockIdx.x >> 7;
    const int i0 = (blockIdx.x & 127) * 4;

    if (tid < 128){
        int r = tid >> 5, k4 = tid & 31;
        *(f32x4*)&hi_s[r][k4*4] = *(const f32x4*)&hi_e[(b*NN + i0 + r)*EHH + k4*4];
        w3_s[tid]  = We1[2*HH*EHH + tid];
        be2_s[tid] = be2[tid];
        bc1_s[tid] = bc1[tid];
        wc2_s[tid] = Wc2[tid];
    }
    if (tid < 12) xi_s[tid/3][tid%3] = x[(b*NN + i0 + tid/3)*3 + tid%3];

    const float rad = (float)radius[0];
    const float r2 = rad * rad;
    const float bc2v = bc2[0];

    // B fragments in registers: bW1 = We2T, bW2 = Wc1T  (col half wn)
    short8 bW1[4][4], bW2[4][4];
    #pragma unroll
    for (int nt = 0; nt < 4; ++nt){
        const int col = wn*64 + nt*16 + l15;
        #pragma unroll
        for (int ks = 0; ks < 4; ++ks){
            bW1[nt][ks] = *(const short8*)&We2T[col*EHH + ks*32 + g*8];
            bW2[nt][ks] = *(const short8*)&Wc1T[col*EHH + ks*32 + g*8];
        }
    }

    float agg_reg[4][4];
    #pragma unroll
    for (int a = 0; a < 4; ++a)
        #pragma unroll
        for (int c2 = 0; c2 < 4; ++c2) agg_reg[a][c2] = 0.f;
    float cx = 0.f, cy = 0.f, cz = 0.f, cw = 0.f;

    __syncthreads();

    #pragma unroll 1
    for (int c = 0; c < 16; ++c){
        const int j0c = c * 32;
        // stage hj + xj
        #pragma unroll
        for (int it = 0; it < 4; ++it){
            int idx = tid + it*256;
            int r = idx >> 5, k4 = idx & 31;
            *(f32x4*)&hj_s[r][k4*4] = *(const f32x4*)&hj_e[(b*NN + j0c + r)*EHH + k4*4];
        }
        if (tid < 96) xj_s[tid/3][tid%3] = x[(b*NN + j0c + tid/3)*3 + tid%3];
        __syncthreads();
        if (tid < 128){
            int il = tid >> 5, jl = tid & 31;
            float d0 = xi_s[il][0] - xj_s[jl][0];
            float d1 = xi_s[il][1] - xj_s[jl][1];
            float d2c = xi_s[il][2] - xj_s[jl][2];
            dx_s[tid][0] = d0; dx_s[tid][1] = d1; dx_s[tid][2] = d2c;
            dx_s[tid][3] = d0*d0 + d1*d1 + d2c*d2c;
        }
        __syncthreads();

        // -------- GEMM1 with fused A-build: m_pre = silu(pre) @ We2 --------
        f32x4 acc[4][4];
        #pragma unroll
        for (int mt = 0; mt < 4; ++mt)
            #pragma unroll
            for (int nt = 0; nt < 4; ++nt) acc[mt][nt] = (f32x4){0.f,0.f,0.f,0.f};

        #pragma unroll
        for (int ks = 0; ks < 4; ++ks){
            short8 afr[4];
            #pragma unroll
            for (int mt = 0; mt < 4; ++mt){
                const int row = wm*64 + mt*16 + l15;
                const int il = row >> 5, jl = row & 31;
                const int kb = ks*32 + g*8;
                f32x4 hia = *(const f32x4*)&hi_s[il][kb];
                f32x4 hib = *(const f32x4*)&hi_s[il][kb+4];
                f32x4 hja = *(const f32x4*)&hj_s[jl][kb];
                f32x4 hjb = *(const f32x4*)&hj_s[jl][kb+4];
                f32x4 w3a = *(const f32x4*)&w3_s[kb];
                f32x4 w3b = *(const f32x4*)&w3_s[kb+4];
                const float d2v = dx_s[row][3];
                short8 av;
                #pragma unroll
                for (int e = 0; e < 4; ++e){
                    float p1 = hia[e] + hja[e] + d2v * w3a[e];
                    float p2 = hib[e] + hjb[e] + d2v * w3b[e];
                    av[e]   = (short)f2bf(fsilu(p1));
                    av[e+4] = (short)f2bf(fsilu(p2));
                }
                afr[mt] = av;
            }
            #pragma unroll
            for (int nt = 0; nt < 4; ++nt)
                #pragma unroll
                for (int mt = 0; mt < 4; ++mt)
                    acc[mt][nt] = __builtin_amdgcn_mfma_f32_16x16x32_bf16(
                        afr[mt], bW1[nt][ks], acc[mt][nt], 0, 0, 0);
        }

        // -------- epilogue 1: m = silu(acc+be2)*mask ; agg += m ; mA = m ---
        #pragma unroll
        for (int mt = 0; mt < 4; ++mt){
            const int rbase = wm*64 + mt*16;
            #pragma unroll
            for (int nt = 0; nt < 4; ++nt){
                const int col = wn*64 + nt*16 + l15;
                const float bbv = be2_s[col];
                f32x4 v = acc[mt][nt];
                #pragma unroll
                for (int rg = 0; rg < 4; ++rg){
                    const int r = rbase + g*4 + rg;
                    const float d2v = dx_s[r][3];
                    const int gi = i0 + (r >> 5), gj = j0c + (r & 31);
                    float m = fsilu(v[rg] + bbv);
                    float mf = (d2v < r2 && gi != gj) ? m : 0.f;
                    agg_reg[mt][nt] += mf;
                    mA[r][col] = f2bf(mf);
                }
            }
        }
        __syncthreads();

        // -------- GEMM2: g1_pre = m @ Wc1 ---------------------------------
        f32x4 acc2[4][4];
        #pragma unroll
        for (int mt = 0; mt < 4; ++mt)
            #pragma unroll
            for (int nt = 0; nt < 4; ++nt) acc2[mt][nt] = (f32x4){0.f,0.f,0.f,0.f};

        #pragma unroll
        for (int ks = 0; ks < 4; ++ks){
            short8 afr[4];
            #pragma unroll
            for (int mt = 0; mt < 4; ++mt)
                afr[mt] = *(const short8*)&mA[wm*64 + mt*16 + l15][ks*32 + g*8];
            #pragma unroll
            for (int nt = 0; nt < 4; ++nt)
                #pragma unroll
                for (int mt = 0; mt < 4; ++mt)
                    acc2[mt][nt] = __builtin_amdgcn_mfma_f32_16x16x32_bf16(
                        afr[mt], bW2[nt][ks], acc2[mt][nt], 0, 0, 0);
        }

        // -------- epilogue 2: gate = silu(acc2+bc1) . Wc2 + bc2 -----------
        float gp[4][4];
        #pragma unroll
        for (int mt = 0; mt < 4; ++mt)
            #pragma unroll
            for (int rg = 0; rg < 4; ++rg) gp[mt][rg] = 0.f;
        #pragma unroll
        for (int mt = 0; mt < 4; ++mt){
            #pragma unroll
            for (int nt = 0; nt < 4; ++nt){
                const int col = wn*64 + nt*16 + l15;
                const float bcc = bc1_s[col], wcc = wc2_s[col];
                f32x4 v = acc2[mt][nt];
                #pragma unroll
                for (int rg = 0; rg < 4; ++rg)
                    gp[mt][rg] += fsilu(v[rg] + bcc) * wcc;
            }
        }
        #pragma unroll
        for (int mt = 0; mt < 4; ++mt){
            #pragma unroll
            for (int rg = 0; rg < 4; ++rg){
                float t = gp[mt][rg];
                t += __shfl_xor(t, 1); t += __shfl_xor(t, 2);
                t += __shfl_xor(t, 4); t += __shfl_xor(t, 8);
                gp[mt][rg] = t;
            }
        }
        if (wn == 0 && l15 == 0){
            #pragma unroll
            for (int mt = 0; mt < 4; ++mt)
                #pragma unroll
                for (int rg = 0; rg < 4; ++rg)
                    gate_s[wm*64 + mt*16 + g*4 + rg] = gp[mt][rg] + bc2v;
        }
        __syncthreads();
        if (wn == 1 && l15 == 0){
            #pragma unroll
            for (int mt = 0; mt < 4; ++mt)
                #pragma unroll
                for (int rg = 0; rg < 4; ++rg)
                    gate_s[wm*64 + mt*16 + g*4 + rg] += gp[mt][rg];
        }
        __syncthreads();

        // -------- coord accumulation --------------------------------------
        if (tid < 128){
            const int r = tid;
            const float d2v = dx_s[r][3];
            const int gi = i0 + (r >> 5), gj = j0c + (r & 31);
            float mf = (d2v < r2 && gi != gj) ? 1.f : 0.f;
            float gv = gate_s[r] * mf;
            float c0 = dx_s[r][0]*gv, c1 = dx_s[r][1]*gv, c2c = dx_s[r][2]*gv;
            #pragma unroll
            for (int m = 1; m <= 16; m <<= 1){
                c0  += __shfl_xor(c0, m);
                c1  += __shfl_xor(c1, m);
                c2c += __shfl_xor(c2c, m);
                mf  += __shfl_xor(mf, m);
            }
            if ((tid & 31) == 0){ cx += c0; cy += c1; cz += c2c; cw += mf; }
        }
        __syncthreads();
    }

    // -------- write agg (no atomics: block owns rows, wave owns quadrant) --
    #pragma unroll
    for (int mt = 0; mt < 4; ++mt){
        #pragma unroll
        for (int nt = 0; nt < 4; ++nt){
            float t = agg_reg[mt][nt];
            t += __shfl_xor(t, 16); t += __shfl_xor(t, 32);
            agg_reg[mt][nt] = t;
        }
    }
    if (lane < 16){
        #pragma unroll
        for (int m2 = 0; m2 < 2; ++m2){
            #pragma unroll
            for (int nt = 0; nt < 4; ++nt){
                const int gi = i0 + wm*2 + m2;
                const int col = wn*64 + nt*16 + lane;
                aggb[(b*NN + gi)*HH + col] = agg_reg[2*m2][nt] + agg_reg[2*m2+1][nt];
            }
        }
    }
    // -------- write x_new --------------------------------------------------
    if (tid < 128 && (tid & 31) == 0){
        const int il = tid >> 5;
        const int gi = i0 + il;
        float cnt = cw > 1.f ? cw : 1.f;
        float inv = 1.0f / cnt;
        xout[(b*NN + gi)*3 + 0] = x[(b*NN + gi)*3 + 0] + cx*inv;
        xout[(b*NN + gi)*3 + 1] = x[(b*NN + gi)*3 + 1] + cy*inv;
        xout[(b*NN + gi)*3 + 2] = x[(b*NN + gi)*3 + 2] + cz*inv;
    }
}

// ---------------- node MLP: h_new = h + MLP(concat(h, agg)) ---------------
__global__ __launch_bounds__(128) void k_node(
    const float* __restrict__ h, const float* __restrict__ aggb,
    const float* __restrict__ Wn1, const float* __restrict__ bn1,
    const float* __restrict__ Wn2, const float* __restrict__ bn2,
    float* __restrict__ hout)
{
    __shared__ float hcat[8][260];
    __shared__ float t1[8][132];
    const int tid = threadIdx.x;
    const int row0 = blockIdx.x * 8;
    #pragma unroll
    for (int r = 0; r < 8; ++r){
        hcat[r][tid]      = h[(row0 + r)*HH + tid];
        hcat[r][HH + tid] = aggb[(row0 + r)*HH + tid];
    }
    __syncthreads();
    float acc[8] = {0.f,0.f,0.f,0.f,0.f,0.f,0.f,0.f};
    #pragma unroll 4
    for (int k = 0; k < 2*HH; ++k){
        float w = Wn1[k*EHH + tid];
        #pragma unroll
        for (int r = 0; r < 8; ++r) acc[r] += hcat[r][k] * w;
    }
    const float bn1v = bn1[tid];
    #pragma unroll
    for (int r = 0; r < 8; ++r) t1[r][tid] = fsilu(acc[r] + bn1v);
    __syncthreads();
    float acc2[8] = {0.f,0.f,0.f,0.f,0.f,0.f,0.f,0.f};
    #pragma unroll 4
    for (int e = 0; e < EHH; ++e){
        float w = Wn2[e*HH + tid];
        #pragma unroll
        for (int r = 0; r < 8; ++r) acc2[r] += t1[r][e] * w;
    }
    const float bn2v = bn2[tid];
    #pragma unroll
    for (int r = 0; r < 8; ++r)
        hout[(row0 + r)*HH + tid] = hcat[r][tid] + acc2[r] + bn2v;
}

extern "C" void kernel_launch(void* const* d_in, const int* in_sizes, int n_in,
                              void* d_out, int out_size, void* d_ws, size_t ws_size,
                              hipStream_t stream) {
    const float* h   = (const float*)d_in[0];
    const float* x   = (const float*)d_in[1];
    const float* We1 = (const float*)d_in[2];
    const float* be1 = (const float*)d_in[3];
    const float* We2 = (const float*)d_in[4];
    const float* be2 = (const float*)d_in[5];
    const float* Wc1 = (const float*)d_in[6];
    const float* bc1 = (const float*)d_in[7];
    const float* Wc2 = (const float*)d_in[8];
    const float* bc2 = (const float*)d_in[9];
    const float* Wn1 = (const float*)d_in[10];
    const float* bn1 = (const float*)d_in[11];
    const float* Wn2 = (const float*)d_in[12];
    const float* bn2 = (const float*)d_in[13];
    const int* radius = (const int*)d_in[14];

    float* out_h = (float*)d_out;
    float* out_x = out_h + BB*NN*HH;

    char* ws = (char*)d_ws;
    float* hi_e = (float*)ws;                                   // 1 MB
    float* hj_e = (float*)(ws + (1 << 20));                     // 1 MB
    unsigned short* We2T = (unsigned short*)(ws + (2 << 20));   // 32 KB
    unsigned short* Wc1T = (unsigned short*)(ws + (2 << 20) + 32768);
    float* aggb = (float*)(ws + (2 << 20) + 65536);             // 1 MB

    k_prep<<<BB*NN + 32, 128, 0, stream>>>(h, We1, be1, We2, Wc1,
                                           hi_e, hj_e, We2T, Wc1T);
    k_edge<<<BB*(NN/4), 256, 0, stream>>>(x, hi_e, hj_e, We2T, Wc1T,
                                          We1, be2, bc1, Wc2, bc2, radius,
                                          aggb, out_x);
    k_node<<<BB*NN/8, 128, 0, stream>>>(h, aggb, Wn1, bn1, Wn2, bn2, out_h);
}